// Round 7
// baseline (394.752 us; speedup 1.0000x reference)
//
#include <hip/hip_runtime.h>

// FeatureExtractor via MFMA bf16 hi/lo, TRANSPOSED orientation.
// R7 = R5 topology (producer + single consumer, depth-4 ring) with BOTH LDS
// round-trips replaced by in-register ds_bpermute lane exchanges:
//  - consumer: h stays in registers; the B-fragment (channels 8q..8q+7 of
//    seq m) is pulled from lanes {m,m+16,m+32,m+48} via 16 bpermutes +
//    cndmask selects. Removes sh write->wait->read->wait (~2 LDS latencies)
//    from the recurrent critical path. Bias ch25 = exact 1.0 cndmask;
//    ch26-31 are finite garbage x exactly-zero weight columns -> +0.0 ->
//    MFMA results BIT-IDENTICAL to R5.
//  - producer: p exchange via 12 bpermutes, removes sp. ch20 bias = 1.0
//    cndmask; ch21-31 garbage x zero weights.
// Ring kept in R6's conflict-free [slot][6][64] layout (16B lane stride).
// R6's tile-split consumers REVERTED: cross-wave rendezvous inside the
// recurrent chain cost +260cy/step (188us); the chain must stay in one wave.
//
// Layouts per verified guide mapping: A[m][k]/B[k][n]: m|n=lane&15,
// k=(lane>>4)*8+j; D: col=lane&15, row=(lane>>4)*4+reg.

typedef __bf16 bf16x8 __attribute__((ext_vector_type(8)));
typedef float  f32x4  __attribute__((ext_vector_type(4)));

#define TT 128
#define CC 25
#define PP 20
#define HH 25
#define NSEQ 16384
#define MFMA __builtin_amdgcn_mfma_f32_16x16x32_bf16
#define LD_ACQ(p)    __hip_atomic_load((p), __ATOMIC_ACQUIRE, __HIP_MEMORY_SCOPE_WORKGROUP)
#define ST_REL(p, v) __hip_atomic_store((p), (v), __ATOMIC_RELEASE, __HIP_MEMORY_SCOPE_WORKGROUP)

__device__ __forceinline__ void split2(float f, __bf16& hi, __bf16& lo) {
    hi = (__bf16)f;
    lo = (__bf16)(f - (float)hi);
}
__device__ __forceinline__ float frcp(float v) { return __builtin_amdgcn_rcpf(v); }
__device__ __forceinline__ float bperm(int addr, float v) {
    return __int_as_float(__builtin_amdgcn_ds_bpermute(addr, __float_as_int(v)));
}

__global__ __launch_bounds__(128, 2) void gru_bp(
    const float* __restrict__ x,   const float* __restrict__ W1,
    const float* __restrict__ b1,  const float* __restrict__ Wih,
    const float* __restrict__ Whh, const float* __restrict__ bih,
    const float* __restrict__ bhh, float* __restrict__ out)
{
    __shared__ f32x4 sgx[4][6][64];         // ring [slot][plane][lane], 16B/lane
    __shared__ int s_prod, s_cons;          // monotone step counters

    const int tid  = threadIdx.x;
    const bool pw  = (tid < 64);            // wave 0 = producer
    const int lane = tid & 63;
    const int m = lane & 15, q = lane >> 4;
    const int n0 = blockIdx.x * 16;

    // bpermute source-lane addresses (byte units, lane*4):
    //   addrA -> lane (m, (q&1)*2)   addrB -> lane (m, (q&1)*2 + 1)
    //   addrC -> lane (m, 0)
    const int addrA = (m + ((q & 1) << 5)) << 2;
    const int addrB = addrA + 64;
    const int addrC = m << 2;

    if (tid == 0) { s_prod = 0; s_cons = 0; }
    __syncthreads();

    // ---- gate weight A-fragments, overlaid by role ----
    // producer: Wg = Wih hi/lo (k<PP, bias at k==PP, else 0)
    // consumer: Wg = Whh hi/lo (k<HH, bias at k==HH, else 0)
    bf16x8 WgH[6], WgL[6], WpH[2], WpL[2];
    {
        const float* Ws = pw ? Wih : Whh;
        const float* bs = pw ? bih : bhh;
        const int kd    = pw ? PP  : HH;
        #pragma unroll
        for (int tt = 0; tt < 6; ++tt) {
            const int g = tt >> 1;                 // 0=r,1=z,2=n
            const int u = (tt & 1) * 16 + m;       // unit within gate
            const bool uv = (u < HH);
            const int row = g * HH + u;
            bf16x8 h8, l8;
            #pragma unroll
            for (int j = 0; j < 8; ++j) {
                const int k = q * 8 + j;
                float v = 0.f;
                if (uv) {
                    if (k < kd)       v = Ws[row * kd + k];
                    else if (k == kd) v = bs[row];
                }
                __bf16 a, b; split2(v, a, b); h8[j] = a; l8[j] = b;
            }
            WgH[tt] = h8; WgL[tt] = l8;
        }
    }
    if (pw) {
        #pragma unroll
        for (int tt = 0; tt < 2; ++tt) {
            const int u = tt * 16 + m;
            const bool uv = (u < PP);
            bf16x8 h8, l8;
            #pragma unroll
            for (int j = 0; j < 8; ++j) {
                const int k = q * 8 + j;
                float v = 0.f;
                if (uv) {
                    if (k < CC)       v = W1[u * CC + k];
                    else if (k == CC) v = b1[u];
                }
                __bf16 a, b; split2(v, a, b); h8[j] = a; l8[j] = b;
            }
            WpH[tt] = h8; WpL[tt] = l8;
        }
    }

    if (pw) {
        // ================= PRODUCER =================
        const float* xrow = x + (size_t)(n0 + m) * (TT * CC);
        const int cbase = (q < 3) ? q * 8 : 21;   // q==3: backward-shifted x4
        float xc[8];

        auto load_x = [&](int t) {
            const float* xr = xrow + t * CC;
            f32x4 va = *(const f32x4*)(xr + cbase);
            f32x4 vb = *(const f32x4*)(xr + cbase + ((q < 3) ? 4 : 0));
            #pragma unroll
            for (int j = 0; j < 8; ++j) {
                float v;
                if (q < 3) v = (j < 4) ? va[j] : vb[j - 4];
                else       v = (j == 0) ? va[3] : (j == 1 ? 1.0f : 0.0f);
                xc[j] = v;
            }
        };

        auto produce = [&](int tc, int slot) {      // slot == tc&3, literal
            bf16x8 xH, xL;
            #pragma unroll
            for (int j = 0; j < 8; ++j) { __bf16 a,b; split2(xc[j],a,b); xH[j]=a; xL[j]=b; }

            {   // prefetch next x; in flight across the rest of this step
                const int tn = (tc + 1 < TT) ? tc + 1 : TT - 1;
                load_x(tn);
            }

            // proj: P[unit][seq] = W1aug * [x;1]  (3-term hi/lo, same order)
            f32x4 p0 = {0.f,0.f,0.f,0.f}, p1 = {0.f,0.f,0.f,0.f};
            p0 = MFMA(WpH[0], xH, p0, 0,0,0);
            p0 = MFMA(WpH[0], xL, p0, 0,0,0);
            p0 = MFMA(WpL[0], xH, p0, 0,0,0);
            p1 = MFMA(WpH[1], xH, p1, 0,0,0);
            p1 = MFMA(WpH[1], xL, p1, 0,0,0);
            p1 = MFMA(WpL[1], xH, p1, 0,0,0);
            #pragma unroll
            for (int r = 0; r < 4; ++r) {
                p0[r] = (p0[r] >= 0.f) ? p0[r] : 0.01f * p0[r];
                p1[r] = (p1[r] >= 0.f) ? p1[r] : 0.01f * p1[r];
            }

            // p exchange D->B via bpermute (no LDS): lane needs ch 8q..8q+7.
            // q=0/1: p0 units from lanes (m,2q),(m,2q+1); q=2: p1 units 16-19
            // from lane (m,0), ch20 = 1.0 bias; rest garbage x zero weights.
            float e[8];
            #pragma unroll
            for (int j = 0; j < 4; ++j) {
                const float pa = bperm(addrA, p0[j]);
                const float pb = bperm(addrB, p0[j]);
                const float pc = bperm(addrC, p1[j]);
                e[j]     = (q == 2) ? pc : pa;
                e[4 + j] = pb;
            }
            e[4] = (q == 2) ? 1.0f : e[4];          // k==20 bias channel

            bf16x8 pH, pL;
            #pragma unroll
            for (int j = 0; j < 8; ++j) {
                __bf16 a, b; split2(e[j], a, b); pH[j] = a; pL[j] = b;
            }

            // ih gate pre-activations -> ring slot (vec-major, conflict-free)
            f32x4* ring = &sgx[slot][0][lane];     // plane stride 64 f32x4
            #pragma unroll
            for (int tp = 0; tp < 2; ++tp) {
                f32x4 acc = {0.f,0.f,0.f,0.f};
                acc = MFMA(WgH[tp], pH, acc, 0,0,0);
                acc = MFMA(WgH[tp], pL, acc, 0,0,0);
                acc = MFMA(WgL[tp], pH, acc, 0,0,0);
                ring[(0 + tp) * 64] = acc;
                f32x4 az = {0.f,0.f,0.f,0.f};
                az = MFMA(WgH[2+tp], pH, az, 0,0,0);
                az = MFMA(WgH[2+tp], pL, az, 0,0,0);
                az = MFMA(WgL[2+tp], pH, az, 0,0,0);
                ring[(2 + tp) * 64] = az;
                f32x4 an = {0.f,0.f,0.f,0.f};
                an = MFMA(WgH[4+tp], pH, an, 0,0,0);
                an = MFMA(WgH[4+tp], pL, an, 0,0,0);
                an = MFMA(WgL[4+tp], pH, an, 0,0,0);
                ring[(4 + tp) * 64] = an;
            }
        };

        load_x(0);
        int known_cons = 0;
        for (int tb = 0; tb < TT; tb += 4) {
            #pragma unroll
            for (int u4 = 0; u4 < 4; ++u4) {
                const int t = tb + u4;
                // slot u4 consumed at step t-4 -> need s_cons >= t-3
                if (t >= 4 && known_cons < t - 3) {
                    do { known_cons = LD_ACQ(&s_cons); } while (known_cons < t - 3);
                }
                produce(t, u4);
                if (lane == 0) ST_REL(&s_prod, t + 1);
            }
        }
    } else {
        // ================= CONSUMER =================
        float ho[2][4] = {{0.f,0.f,0.f,0.f},{0.f,0.f,0.f,0.f}};
        int known_prod = 0;

        auto consume = [&](int t, int slot) {       // slot == t&3, literal
            // h exchange D->B via bpermute (h never touches LDS).
            // lane needs ch 8q..8q+7: q<2 from ho[0] of lanes (m,2q),(m,2q+1);
            // q>=2 from ho[1] of lanes (m,(2q)&3),(m,((2q)&3)+1).
            // ch25 = 1.0 bias; ch26-31 garbage x zero weight cols -> +0.0.
            float e[8];
            #pragma unroll
            for (int j = 0; j < 4; ++j) {
                const float a0 = bperm(addrA, ho[0][j]);
                const float a1 = bperm(addrA, ho[1][j]);
                const float b0 = bperm(addrB, ho[0][j]);
                const float b1 = bperm(addrB, ho[1][j]);
                e[j]     = (q < 2) ? a0 : a1;
                e[4 + j] = (q < 2) ? b0 : b1;
            }
            e[1] = (q == 3) ? 1.0f : e[1];          // k==25 bias channel

            bf16x8 hH, hL;
            #pragma unroll
            for (int j = 0; j < 8; ++j) {
                __bf16 a, b; split2(e[j], a, b); hH[j] = a; hL[j] = b;
            }

            const f32x4* rc = &sgx[slot][0][lane];
            f32x4 aR[2], aZ[2], aHn[2], gN[2];
            #pragma unroll
            for (int tp = 0; tp < 2; ++tp) {
                f32x4 acc = rc[(0 + tp) * 64];        // = ih terms, same order
                acc = MFMA(WgH[tp], hH, acc, 0,0,0);
                acc = MFMA(WgH[tp], hL, acc, 0,0,0);
                acc = MFMA(WgL[tp], hH, acc, 0,0,0);
                aR[tp] = acc;
                f32x4 az = rc[(2 + tp) * 64];
                az = MFMA(WgH[2+tp], hH, az, 0,0,0);
                az = MFMA(WgH[2+tp], hL, az, 0,0,0);
                az = MFMA(WgL[2+tp], hH, az, 0,0,0);
                aZ[tp] = az;
                gN[tp] = rc[(4 + tp) * 64];
                f32x4 ah = {0.f,0.f,0.f,0.f};
                ah = MFMA(WgH[4+tp], hH, ah, 0,0,0);
                ah = MFMA(WgH[4+tp], hL, ah, 0,0,0);
                ah = MFMA(WgL[4+tp], hH, ah, 0,0,0);
                aHn[tp] = ah;
            }
            // nonlinearity (rcp-based) + h update, all in registers
            #pragma unroll
            for (int tp = 0; tp < 2; ++tp) {
                #pragma unroll
                for (int r = 0; r < 4; ++r) {
                    const float rg = frcp(1.f + __expf(-aR[tp][r]));
                    const float zg = frcp(1.f + __expf(-aZ[tp][r]));
                    const float nv = gN[tp][r] + rg * aHn[tp][r];
                    const float ee = __expf(-2.f * nv);
                    const float ng = 2.f * frcp(1.f + ee) - 1.f;     // tanh
                    ho[tp][r] = zg * (ho[tp][r] - ng) + ng;          // (1-z)n + z h
                }
            }
        };

        for (int tb = 0; tb < TT; tb += 4) {
            #pragma unroll
            for (int u4 = 0; u4 < 4; ++u4) {
                const int t = tb + u4;
                if (known_prod < t + 1) {
                    do { known_prod = LD_ACQ(&s_prod); } while (known_prod < t + 1);
                }
                consume(t, u4);
                if (lane == 0) ST_REL(&s_cons, t + 1);
            }
        }

        // ---- epilogue: out[seq][unit] ----
        float* orow = out + (size_t)(n0 + m) * HH;
        #pragma unroll
        for (int tp = 0; tp < 2; ++tp) {
            #pragma unroll
            for (int r = 0; r < 4; ++r) {
                const int u = tp * 16 + 4 * q + r;
                if (u < HH) orow[u] = ho[tp][r];
            }
        }
    }
}

extern "C" void kernel_launch(void* const* d_in, const int* in_sizes, int n_in,
                              void* d_out, int out_size, void* d_ws, size_t ws_size,
                              hipStream_t stream) {
    const float* x   = (const float*)d_in[0];
    const float* W1  = (const float*)d_in[1];
    const float* b1  = (const float*)d_in[2];
    const float* Wih = (const float*)d_in[3];
    const float* Whh = (const float*)d_in[4];
    const float* bih = (const float*)d_in[5];
    const float* bhh = (const float*)d_in[6];
    float* out = (float*)d_out;

    gru_bp<<<NSEQ / 16, 128, 0, stream>>>(x, W1, b1, Wih, Whh, bih, bhh, out);
}